// Round 1
// baseline (904.530 us; speedup 1.0000x reference)
//
#include <hip/hip_runtime.h>

// Problem constants
// B=2, S=2048, E=512, H=8, D=64, EDGE=16
#define NB 2
#define NS 2048
#define NE 512
#define NH 8
#define ND 64
#define NEDGE 16

typedef unsigned short u16;
typedef __attribute__((ext_vector_type(4))) float f32x4;
typedef __attribute__((ext_vector_type(8))) short bf16x8;

__device__ __forceinline__ u16 f2bf(float f) {
  unsigned u = __float_as_uint(f);
  u += 0x7FFFu + ((u >> 16) & 1u);
  return (u16)(u >> 16);
}
__device__ __forceinline__ float bf2f(u16 h) {
  return __uint_as_float(((unsigned)h) << 16);
}
__device__ __forceinline__ void gload16(const void* g, void* l) {
  __builtin_amdgcn_global_load_lds(
      (const __attribute__((address_space(1))) unsigned*)g,
      (__attribute__((address_space(3))) unsigned*)l, 16, 0, 0);
}

// ------------------------- K1: f32 -> bf16 convert -------------------------
__global__ void k_cvt(const float* __restrict__ in, u16* __restrict__ out, int n4) {
  int i = blockIdx.x * 256 + threadIdx.x;
  if (i >= n4) return;
  float4 v = ((const float4*)in)[i];
  ushort4 o;
  o.x = f2bf(v.x); o.y = f2bf(v.y); o.z = f2bf(v.z); o.w = f2bf(v.w);
  ((ushort4*)out)[i] = o;
}

// --------------------- shared 128x128 GEMM core (K=512) ---------------------
// A: [M][512] bf16 row-major, W: [n][512] bf16 row-major (B^T layout).
// 256 threads = 4 waves in 2x2; each wave computes 64x64 via 4x4 16x16 frags.
__device__ __forceinline__ void gemm128_core(const u16* __restrict__ A,
                                             const u16* __restrict__ W,
                                             u16* As, u16* Bs,
                                             int mt, f32x4 acc[4][4]) {
  const int tid = threadIdx.x, wave = tid >> 6, lane = tid & 63;
  const int g = lane >> 4, c = lane & 15;
  const int wm = wave >> 1, wn = wave & 1;
  for (int kt = 0; kt < 16; ++kt) {
#pragma unroll
    for (int r = 0; r < 2; ++r) {
      int seg = wave + 4 * r;          // wave-uniform
      int idx = seg * 64 + lane;       // 16B-unit index within 8KB tile
      int row = idx >> 2, colB = idx & 3;
      gload16(A + (size_t)(mt * 128 + row) * 512 + kt * 32 + colB * 8,
              (char*)As + seg * 1024);
      gload16(W + (size_t)row * 512 + kt * 32 + colB * 8,
              (char*)Bs + seg * 1024);
    }
    __syncthreads();
    bf16x8 af[4], bw[4];
#pragma unroll
    for (int mb = 0; mb < 4; ++mb)
      af[mb] = *(const bf16x8*)&As[(wm * 64 + mb * 16 + c) * 32 + 8 * g];
#pragma unroll
    for (int nb = 0; nb < 4; ++nb)
      bw[nb] = *(const bf16x8*)&Bs[(wn * 64 + nb * 16 + c) * 32 + 8 * g];
#pragma unroll
    for (int mb = 0; mb < 4; ++mb)
#pragma unroll
      for (int nb = 0; nb < 4; ++nb)
        acc[mb][nb] = __builtin_amdgcn_mfma_f32_16x16x32_bf16(
            af[mb], bw[nb], acc[mb][nb], 0, 0, 0);
    __syncthreads();
  }
}

// ------------------- K2: packed QKV projection (bf16 MFMA) ------------------
// grid (32, 12): y/4 selects chunk (0=q,1=k,2=v). Writes:
//   qh[bh][s][d] (scaled by 0.125), kh[bh][s][d], vt[bh][d][s]
__launch_bounds__(256)
__global__ void k_proj(const u16* __restrict__ qbf, const u16* __restrict__ kbf,
                       const u16* __restrict__ vbf, const u16* __restrict__ wbf,
                       const float* __restrict__ bin,
                       u16* __restrict__ qh, u16* __restrict__ kh,
                       u16* __restrict__ vt) {
  __shared__ __align__(16) u16 As[4096];
  __shared__ __align__(16) u16 Bs[4096];
  const int tid = threadIdx.x, wave = tid >> 6, lane = tid & 63;
  const int g = lane >> 4, c = lane & 15;
  const int wm = wave >> 1, wn = wave & 1;
  const int mt = blockIdx.x;
  const int chunk = blockIdx.y >> 2, ntl = blockIdx.y & 3;
  const u16* A = chunk == 0 ? qbf : (chunk == 1 ? kbf : vbf);
  const u16* W = wbf + (size_t)(chunk * 512 + ntl * 128) * 512;

  f32x4 acc[4][4];
#pragma unroll
  for (int i = 0; i < 4; ++i)
#pragma unroll
    for (int j = 0; j < 4; ++j) acc[i][j] = (f32x4){0.f, 0.f, 0.f, 0.f};

  gemm128_core(A, W, As, Bs, mt, acc);

#pragma unroll
  for (int mb = 0; mb < 4; ++mb) {
#pragma unroll
    for (int nb = 0; nb < 4; ++nb) {
      int ncl = ntl * 128 + wn * 64 + nb * 16 + c;   // 0..511 within chunk
      float bv = bin[chunk * 512 + ncl];
      int h = ncl >> 6, d = ncl & 63;
      int m0 = mt * 128 + wm * 64 + mb * 16 + g * 4;
      int b = m0 >> 11, s0 = m0 & 2047;
      if (chunk == 2) {
        ushort4 o;
        o.x = f2bf(acc[mb][nb][0] + bv);
        o.y = f2bf(acc[mb][nb][1] + bv);
        o.z = f2bf(acc[mb][nb][2] + bv);
        o.w = f2bf(acc[mb][nb][3] + bv);
        *(ushort4*)&vt[((size_t)(b * 8 + h) * 64 + d) * 2048 + s0] = o;
      } else {
        u16* dst = (chunk == 0) ? qh : kh;
        float sc = (chunk == 0) ? 0.125f : 1.0f;   // fold 1/sqrt(64) into q
#pragma unroll
        for (int r = 0; r < 4; ++r)
          dst[((size_t)(b * 8 + h) * 2048 + s0 + r) * 64 + d] =
              f2bf((acc[mb][nb][r] + bv) * sc);
      }
    }
  }
}

// ---------------- K3: edge bias  bias[b][h][q][k] (bf16) --------------------
// one thread per (b,q,k) pair; q restricted to chunk [q0, q0+QC)
__launch_bounds__(256)
__global__ void k_bias(const float* __restrict__ p, const float* __restrict__ ewg,
                       const float* __restrict__ ebg, u16* __restrict__ bias,
                       int q0, int QC) {
  __shared__ float ew[NH * NEDGE];
  __shared__ float eb[NH];
  int tid = threadIdx.x;
  if (tid < NH * NEDGE) ew[tid] = ewg[tid];
  if (tid < NH) eb[tid] = ebg[tid];
  __syncthreads();
  int pi = blockIdx.x * 256 + tid;
  int total = NB * QC * NS;
  if (pi >= total) return;
  int k = pi & (NS - 1);
  int t2 = pi >> 11;              // b*QC + ql
  int b = (t2 >= QC) ? 1 : 0;
  int ql = t2 - b * QC;
  int q = q0 + ql;

  const float* pv = p + (((size_t)(b * NS + q) * NS) + k) * NEDGE;
  float4 v0 = ((const float4*)pv)[0];
  float4 v1 = ((const float4*)pv)[1];
  float4 v2 = ((const float4*)pv)[2];
  float4 v3 = ((const float4*)pv)[3];
  float x[16] = {v0.x, v0.y, v0.z, v0.w, v1.x, v1.y, v1.z, v1.w,
                 v2.x, v2.y, v2.z, v2.w, v3.x, v3.y, v3.z, v3.w};
  float acc[NH];
#pragma unroll
  for (int h = 0; h < NH; ++h) {
    float a = eb[h];
#pragma unroll
    for (int e = 0; e < NEDGE; ++e) a += x[e] * ew[h * NEDGE + e];
    acc[h] = a;
  }
#pragma unroll
  for (int h = 0; h < NH; ++h)
    bias[((size_t)(b * 8 + h) * QC + ql) * NS + k] = f2bf(acc[h]);
}

// --------------------- K4: flash attention w/ bias --------------------------
// block = (qt, h, b); 4 waves x 16 q-rows. KV tiles of 64.
__device__ __forceinline__ float redmax16(float x) {
  x = fmaxf(x, __shfl_xor(x, 1));
  x = fmaxf(x, __shfl_xor(x, 2));
  x = fmaxf(x, __shfl_xor(x, 4));
  x = fmaxf(x, __shfl_xor(x, 8));
  return x;
}
__device__ __forceinline__ float redsum16(float x) {
  x += __shfl_xor(x, 1); x += __shfl_xor(x, 2);
  x += __shfl_xor(x, 4); x += __shfl_xor(x, 8);
  return x;
}

__launch_bounds__(256)
__global__ void k_attn(const u16* __restrict__ qh, const u16* __restrict__ kh,
                       const u16* __restrict__ vt, const u16* __restrict__ biasb,
                       u16* __restrict__ ctx, int q0, int QC) {
  __shared__ __align__(16) u16 P_s[4 * 16 * 64];
  const int tid = threadIdx.x, wave = tid >> 6, lane = tid & 63;
  const int g = lane >> 4, c = lane & 15;
  const int qt = blockIdx.x, h = blockIdx.y, b = blockIdx.z;
  const int bh = b * 8 + h;
  const int q_chunk = qt * 64 + wave * 16;   // within chunk
  const int q_glob = q0 + q_chunk;           // global s
  u16* Pw = P_s + wave * 1024;

  // Q fragments (A-operand): row = c, k(d) contiguous
  const u16* Qb = qh + ((size_t)bh * 2048 + q_glob + c) * 64;
  bf16x8 qf0 = *(const bf16x8*)(Qb + 8 * g);
  bf16x8 qf1 = *(const bf16x8*)(Qb + 32 + 8 * g);

  const u16* Kb = kh + (size_t)bh * 2048 * 64;
  const u16* Vb = vt + (size_t)bh * 64 * 2048;
  const u16* Bb = biasb + (size_t)bh * QC * 2048;

  f32x4 o[4];
#pragma unroll
  for (int i = 0; i < 4; ++i) o[i] = (f32x4){0.f, 0.f, 0.f, 0.f};
  float mrow[4] = {-1e30f, -1e30f, -1e30f, -1e30f};
  float lrow[4] = {0.f, 0.f, 0.f, 0.f};

  for (int kt = 0; kt < 2048; kt += 64) {
    // ---- QK^T (scores for 16q x 64k) ----
    f32x4 sc[4];
#pragma unroll
    for (int nb = 0; nb < 4; ++nb) {
      const u16* kp = Kb + (size_t)(kt + nb * 16 + c) * 64 + 8 * g;
      bf16x8 b0 = *(const bf16x8*)kp;
      bf16x8 b1 = *(const bf16x8*)(kp + 32);
      f32x4 z = (f32x4){0.f, 0.f, 0.f, 0.f};
      z = __builtin_amdgcn_mfma_f32_16x16x32_bf16(qf0, b0, z, 0, 0, 0);
      z = __builtin_amdgcn_mfma_f32_16x16x32_bf16(qf1, b1, z, 0, 0, 0);
      sc[nb] = z;
    }
    // ---- add bias ----
#pragma unroll
    for (int nb = 0; nb < 4; ++nb) {
#pragma unroll
      for (int r = 0; r < 4; ++r) {
        int ql_ = q_chunk + g * 4 + r;
        sc[nb][r] += bf2f(Bb[(size_t)ql_ * 2048 + kt + nb * 16 + c]);
      }
    }
    // ---- online softmax ----
    float mnew[4], scl[4];
#pragma unroll
    for (int r = 0; r < 4; ++r) {
      float mx = fmaxf(fmaxf(sc[0][r], sc[1][r]), fmaxf(sc[2][r], sc[3][r]));
      mx = redmax16(mx);
      mnew[r] = fmaxf(mrow[r], mx);
      scl[r] = __expf(mrow[r] - mnew[r]);
      mrow[r] = mnew[r];
    }
    float rsum[4] = {0.f, 0.f, 0.f, 0.f};
#pragma unroll
    for (int nb = 0; nb < 4; ++nb)
#pragma unroll
      for (int r = 0; r < 4; ++r) {
        float e = __expf(sc[nb][r] - mnew[r]);
        sc[nb][r] = e;
        rsum[r] += e;
      }
#pragma unroll
    for (int r = 0; r < 4; ++r) {
      float s = redsum16(rsum[r]);
      lrow[r] = lrow[r] * scl[r] + s;
    }
#pragma unroll
    for (int nd = 0; nd < 4; ++nd)
#pragma unroll
      for (int r = 0; r < 4; ++r) o[nd][r] *= scl[r];

    // ---- P -> LDS (bf16, XOR-swizzled on k bits 3..5) ----
#pragma unroll
    for (int nb = 0; nb < 4; ++nb)
#pragma unroll
      for (int r = 0; r < 4; ++r) {
        int rr = g * 4 + r, kk = nb * 16 + c;
        Pw[rr * 64 + (kk ^ ((rr & 7) << 3))] = f2bf(sc[nb][r]);
      }
    // ---- PV: A = P (from LDS), B = V^T (contiguous from vt) ----
    bf16x8 pa0, pa1;
    {
      int rr = c;
      pa0 = *(const bf16x8*)&Pw[rr * 64 + ((8 * g) ^ ((rr & 7) << 3))];
      pa1 = *(const bf16x8*)&Pw[rr * 64 + ((32 + 8 * g) ^ ((rr & 7) << 3))];
    }
#pragma unroll
    for (int nd = 0; nd < 4; ++nd) {
      const u16* vp = Vb + (size_t)(nd * 16 + c) * 2048 + kt;
      bf16x8 v0 = *(const bf16x8*)(vp + 8 * g);
      bf16x8 v1 = *(const bf16x8*)(vp + 32 + 8 * g);
      o[nd] = __builtin_amdgcn_mfma_f32_16x16x32_bf16(pa0, v0, o[nd], 0, 0, 0);
      o[nd] = __builtin_amdgcn_mfma_f32_16x16x32_bf16(pa1, v1, o[nd], 0, 0, 0);
    }
  }
  // ---- normalize + write ctx (bf16 [b][s][h*64+d]) ----
  float inv[4];
#pragma unroll
  for (int r = 0; r < 4; ++r) inv[r] = 1.0f / lrow[r];
#pragma unroll
  for (int nd = 0; nd < 4; ++nd)
#pragma unroll
    for (int r = 0; r < 4; ++r) {
      int s_glob = q_glob + g * 4 + r;
      ctx[(size_t)(b * 2048 + s_glob) * 512 + h * 64 + nd * 16 + c] =
          f2bf(o[nd][r] * inv[r]);
    }
}

// ------------------------ K5: output projection -----------------------------
__launch_bounds__(256)
__global__ void k_outproj(const u16* __restrict__ ctx, const u16* __restrict__ wobf,
                          const float* __restrict__ bout, float* __restrict__ out) {
  __shared__ __align__(16) u16 As[4096];
  __shared__ __align__(16) u16 Bs[4096];
  const int tid = threadIdx.x, wave = tid >> 6, lane = tid & 63;
  const int g = lane >> 4, c = lane & 15;
  const int wm = wave >> 1, wn = wave & 1;
  const int mt = blockIdx.x, nt = blockIdx.y;
  const u16* W = wobf + (size_t)(nt * 128) * 512;

  f32x4 acc[4][4];
#pragma unroll
  for (int i = 0; i < 4; ++i)
#pragma unroll
    for (int j = 0; j < 4; ++j) acc[i][j] = (f32x4){0.f, 0.f, 0.f, 0.f};

  gemm128_core(ctx, W, As, Bs, mt, acc);

#pragma unroll
  for (int mb = 0; mb < 4; ++mb)
#pragma unroll
    for (int nb = 0; nb < 4; ++nb) {
      int n = nt * 128 + wn * 64 + nb * 16 + c;
      float bv = bout[n];
      int m0 = mt * 128 + wm * 64 + mb * 16 + g * 4;
#pragma unroll
      for (int r = 0; r < 4; ++r)
        out[(size_t)(m0 + r) * 512 + n] = acc[mb][nb][r] + bv;
    }
}

// ---------------------------------------------------------------------------
extern "C" void kernel_launch(void* const* d_in, const int* in_sizes, int n_in,
                              void* d_out, int out_size, void* d_ws, size_t ws_size,
                              hipStream_t stream) {
  (void)in_sizes; (void)n_in; (void)out_size;
  const float* q     = (const float*)d_in[0];
  const float* k     = (const float*)d_in[1];
  const float* v     = (const float*)d_in[2];
  const float* p     = (const float*)d_in[3];
  const float* w_in  = (const float*)d_in[4];
  const float* b_in  = (const float*)d_in[5];
  const float* w_out = (const float*)d_in[6];
  const float* b_out = (const float*)d_in[7];
  const float* ew    = (const float*)d_in[8];
  const float* eb    = (const float*)d_in[9];
  float* out = (float*)d_out;

  char* ws = (char*)d_ws;
  size_t off = 0;
  auto alloc = [&](size_t bytes) {
    void* r = ws + off;
    off += (bytes + 255) & ~(size_t)255;
    return r;
  };
  const size_t NTOK = (size_t)NB * NS;            // 4096
  u16* qbf  = (u16*)alloc(NTOK * NE * 2);
  u16* kbf  = (u16*)alloc(NTOK * NE * 2);
  u16* vbf  = (u16*)alloc(NTOK * NE * 2);
  u16* wbf  = (u16*)alloc((size_t)3 * NE * NE * 2);
  u16* wobf = (u16*)alloc((size_t)NE * NE * 2);
  u16* qhb  = (u16*)alloc(NTOK * NE * 2);
  u16* khb  = (u16*)alloc(NTOK * NE * 2);
  u16* vtb  = (u16*)alloc(NTOK * NE * 2);
  u16* ctxb = (u16*)alloc(NTOK * NE * 2);

  size_t rem = (ws_size > off) ? (ws_size - off) : 0;
  int QC = 2048;
  while (QC > 64 && (size_t)NB * NH * QC * NS * 2 > rem) QC >>= 1;
  u16* biasb = (u16*)alloc((size_t)NB * NH * QC * NS * 2);

  // K1: converts
  int n4;
  n4 = (int)(NTOK * NE / 4);
  k_cvt<<<n4 / 256, 256, 0, stream>>>(q, qbf, n4);
  k_cvt<<<n4 / 256, 256, 0, stream>>>(k, kbf, n4);
  k_cvt<<<n4 / 256, 256, 0, stream>>>(v, vbf, n4);
  n4 = 3 * NE * NE / 4;
  k_cvt<<<n4 / 256, 256, 0, stream>>>(w_in, wbf, n4);
  n4 = NE * NE / 4;
  k_cvt<<<n4 / 256, 256, 0, stream>>>(w_out, wobf, n4);

  // K2: projections
  k_proj<<<dim3(32, 12), 256, 0, stream>>>(qbf, kbf, vbf, wbf, b_in, qhb, khb, vtb);

  // K3/K4 per q-chunk
  for (int q0 = 0; q0 < NS; q0 += QC) {
    int pairs = NB * QC * NS;
    k_bias<<<pairs / 256, 256, 0, stream>>>(p, ew, eb, biasb, q0, QC);
    k_attn<<<dim3(QC / 64, NH, NB), 256, 0, stream>>>(qhb, khb, vtb, biasb, ctxb, q0, QC);
  }

  // K5: out projection
  k_outproj<<<dim3(32, 4), 256, 0, stream>>>(ctxb, wobf, b_out, out);
}

// Round 2
// 894.077 us; speedup vs baseline: 1.0117x; 1.0117x over previous
//
#include <hip/hip_runtime.h>

// Problem constants: B=2, S=2048, E=512, H=8, D=64, EDGE=16
#define NB 2
#define NS 2048
#define NE 512
#define NH 8
#define ND 64
#define NEDGE 16

typedef unsigned short u16;
typedef __attribute__((ext_vector_type(4))) float f32x4;
typedef __attribute__((ext_vector_type(8))) short bf16x8;

__device__ __forceinline__ u16 f2bf(float f) {
  unsigned u = __float_as_uint(f);
  u += 0x7FFFu + ((u >> 16) & 1u);
  return (u16)(u >> 16);
}
__device__ __forceinline__ void gload16(const void* g, void* l) {
  __builtin_amdgcn_global_load_lds(
      (const __attribute__((address_space(1))) unsigned*)g,
      (__attribute__((address_space(3))) unsigned*)l, 16, 0, 0);
}

// ------------------------- K1: f32 -> bf16 convert -------------------------
__global__ void k_cvt(const float* __restrict__ in, u16* __restrict__ out, int n4) {
  int i = blockIdx.x * 256 + threadIdx.x;
  if (i >= n4) return;
  float4 v = ((const float4*)in)[i];
  ushort4 o;
  o.x = f2bf(v.x); o.y = f2bf(v.y); o.z = f2bf(v.z); o.w = f2bf(v.w);
  ((ushort4*)out)[i] = o;
}

// --------------------- shared 128x128 GEMM core (K=512) ---------------------
__device__ __forceinline__ void gemm128_core(const u16* __restrict__ A,
                                             const u16* __restrict__ W,
                                             u16* As, u16* Bs,
                                             int mt, f32x4 acc[4][4]) {
  const int tid = threadIdx.x, wave = tid >> 6, lane = tid & 63;
  const int g = lane >> 4, c = lane & 15;
  const int wm = wave >> 1, wn = wave & 1;
  for (int kt = 0; kt < 16; ++kt) {
#pragma unroll
    for (int r = 0; r < 2; ++r) {
      int seg = wave + 4 * r;
      int idx = seg * 64 + lane;
      int row = idx >> 2, colB = idx & 3;
      gload16(A + (size_t)(mt * 128 + row) * 512 + kt * 32 + colB * 8,
              (char*)As + seg * 1024);
      gload16(W + (size_t)row * 512 + kt * 32 + colB * 8,
              (char*)Bs + seg * 1024);
    }
    __syncthreads();
    bf16x8 af[4], bw[4];
#pragma unroll
    for (int mb = 0; mb < 4; ++mb)
      af[mb] = *(const bf16x8*)&As[(wm * 64 + mb * 16 + c) * 32 + 8 * g];
#pragma unroll
    for (int nb = 0; nb < 4; ++nb)
      bw[nb] = *(const bf16x8*)&Bs[(wn * 64 + nb * 16 + c) * 32 + 8 * g];
#pragma unroll
    for (int mb = 0; mb < 4; ++mb)
#pragma unroll
      for (int nb = 0; nb < 4; ++nb)
        acc[mb][nb] = __builtin_amdgcn_mfma_f32_16x16x32_bf16(
            af[mb], bw[nb], acc[mb][nb], 0, 0, 0);
    __syncthreads();
  }
}

// ------------------- K2: packed QKV projection (bf16 MFMA) ------------------
__launch_bounds__(256)
__global__ void k_proj(const u16* __restrict__ qbf, const u16* __restrict__ kbf,
                       const u16* __restrict__ vbf, const u16* __restrict__ wbf,
                       const float* __restrict__ bin,
                       u16* __restrict__ qh, u16* __restrict__ kh,
                       u16* __restrict__ vt) {
  __shared__ __align__(16) u16 As[4096];
  __shared__ __align__(16) u16 Bs[4096];
  const int tid = threadIdx.x, wave = tid >> 6, lane = tid & 63;
  const int g = lane >> 4, c = lane & 15;
  const int wm = wave >> 1, wn = wave & 1;
  const int mt = blockIdx.x;
  const int chunk = blockIdx.y >> 2, ntl = blockIdx.y & 3;
  const u16* A = chunk == 0 ? qbf : (chunk == 1 ? kbf : vbf);
  const u16* W = wbf + (size_t)(chunk * 512 + ntl * 128) * 512;

  f32x4 acc[4][4];
#pragma unroll
  for (int i = 0; i < 4; ++i)
#pragma unroll
    for (int j = 0; j < 4; ++j) acc[i][j] = (f32x4){0.f, 0.f, 0.f, 0.f};

  gemm128_core(A, W, As, Bs, mt, acc);

#pragma unroll
  for (int mb = 0; mb < 4; ++mb) {
#pragma unroll
    for (int nb = 0; nb < 4; ++nb) {
      int ncl = ntl * 128 + wn * 64 + nb * 16 + c;
      float bv = bin[chunk * 512 + ncl];
      int h = ncl >> 6, d = ncl & 63;
      int m0 = mt * 128 + wm * 64 + mb * 16 + g * 4;
      int b = m0 >> 11, s0 = m0 & 2047;
      if (chunk == 2) {
        ushort4 o;
        o.x = f2bf(acc[mb][nb][0] + bv);
        o.y = f2bf(acc[mb][nb][1] + bv);
        o.z = f2bf(acc[mb][nb][2] + bv);
        o.w = f2bf(acc[mb][nb][3] + bv);
        *(ushort4*)&vt[((size_t)(b * 8 + h) * 64 + d) * 2048 + s0] = o;
      } else {
        u16* dst = (chunk == 0) ? qh : kh;
        float sc = (chunk == 0) ? 0.125f : 1.0f;
#pragma unroll
        for (int r = 0; r < 4; ++r)
          dst[((size_t)(b * 8 + h) * 2048 + s0 + r) * 64 + d] =
              f2bf((acc[mb][nb][r] + bv) * sc);
      }
    }
  }
}

// ------------- K3: fused edge-bias + flash attention (all heads) ------------
// block = (b, 16 q-rows); 512 threads = 8 waves = 8 heads.
// p tile [16q][64k][16e] f32 double-buffered in LDS via global_load_lds,
// chunk-placement XOR-swizzled on the GLOBAL source (LDS dest must be linear).
__device__ __forceinline__ float redmax16(float x) {
  x = fmaxf(x, __shfl_xor(x, 1));
  x = fmaxf(x, __shfl_xor(x, 2));
  x = fmaxf(x, __shfl_xor(x, 4));
  x = fmaxf(x, __shfl_xor(x, 8));
  return x;
}
__device__ __forceinline__ float redsum16(float x) {
  x += __shfl_xor(x, 1); x += __shfl_xor(x, 2);
  x += __shfl_xor(x, 4); x += __shfl_xor(x, 8);
  return x;
}

__launch_bounds__(512, 2)
__global__ void k_fattn(const float* __restrict__ p,
                        const float* __restrict__ ewg, const float* __restrict__ ebg,
                        const u16* __restrict__ qh, const u16* __restrict__ kh,
                        const u16* __restrict__ vt, u16* __restrict__ ctx) {
  __shared__ __align__(16) float p_s[2][16384];   // 2 x 64 KB
  __shared__ __align__(16) u16 P_s[8][1024];      // 16 KB (per-wave P tiles)
  const int tid = threadIdx.x;
  const int wave = tid >> 6, lane = tid & 63;
  const int g = lane >> 4, c = lane & 15;
  const int h = wave;
  // XCD-aware block mapping: XCDs 0-3 -> b=0, 4-7 -> b=1 (keeps each b's
  // 4MB K/V slice resident in 4 XCD L2s)
  const int bid = blockIdx.x;
  const int xcd = bid & 7, idx = bid >> 3;
  const int b = xcd >> 2;
  const int qt = (xcd & 3) * 32 + idx;   // 0..127
  const int q0 = qt * 16;
  const int bh = b * 8 + h;
  const int sl = (c >> 1) & 3;           // per-lane chunk swizzle key
  u16* Pw = P_s[wave];

  // this head's edge weights -> registers
  float ewh[16];
#pragma unroll
  for (int e = 0; e < 16; ++e) ewh[e] = ewg[h * 16 + e];
  const float ebh = ebg[h];

  // Q fragments (16 rows), hoisted
  const u16* Qb = qh + ((size_t)bh * 2048 + q0 + c) * 64;
  bf16x8 qf0 = *(const bf16x8*)(Qb + 8 * g);
  bf16x8 qf1 = *(const bf16x8*)(Qb + 32 + 8 * g);
  const u16* Kb = kh + (size_t)bh * 2048 * 64;
  const u16* Vb = vt + (size_t)bh * 64 * 2048;

  // p staging: 8 x 16B per thread per tile. LDS slot u = q*256 + k*4 + ecp
  // holds logical chunk ecl = ecp ^ ((k>>1)&3) (source pre-swizzle).
  const float* pb = p + (size_t)(b * 2048 + q0) * 2048 * 16;
  int soff[8], doff[8];
#pragma unroll
  for (int i = 0; i < 8; ++i) {
    int u = i * 512 + tid;
    int ecp = u & 3, kk = (u >> 2) & 63, qq = u >> 8;
    int ecl = ecp ^ ((kk >> 1) & 3);
    soff[i] = (qq * 2048 + kk) * 16 + ecl * 4;  // float offset (+ kt*16 per tile)
    doff[i] = u * 16;                           // byte offset within buffer
  }

  f32x4 o[4];
#pragma unroll
  for (int i = 0; i < 4; ++i) o[i] = (f32x4){0.f, 0.f, 0.f, 0.f};
  float mrow[4] = {-1e30f, -1e30f, -1e30f, -1e30f};
  float lrow[4] = {0.f, 0.f, 0.f, 0.f};

  // prologue: stage tile 0 into buffer 0
#pragma unroll
  for (int i = 0; i < 8; ++i)
    gload16(pb + soff[i], (char*)p_s + doff[i]);

  for (int t = 0; t < 32; ++t) {
    const int kt = t * 64;
    // current buffer's 8 loads are the oldest outstanding -> drain them.
    asm volatile("s_waitcnt vmcnt(0)" ::: "memory");
    __builtin_amdgcn_s_barrier();
    __builtin_amdgcn_sched_barrier(0);
    // prefetch next p tile into other buffer (safe: all waves past barrier)
    if (t < 31) {
      const float* src = pb + (size_t)(kt + 64) * 16;
      char* dst = (char*)p_s + ((t + 1) & 1) * 65536;
#pragma unroll
      for (int i = 0; i < 8; ++i)
        gload16(src + soff[i], dst + doff[i]);
    }
    __builtin_amdgcn_sched_barrier(0);   // keep prefetch issue above compute
    const float* pc = p_s[t & 1];

    // ---- bias for this head's 16x64 fragment, straight from LDS ----
    float bv[4][4];
#pragma unroll
    for (int nb = 0; nb < 4; ++nb) {
#pragma unroll
      for (int r = 0; r < 4; ++r) {
        const float* ps = pc + (g * 4 + r) * 1024 + (nb * 16 + c) * 16;
        f32x4 a0 = *(const f32x4*)(ps + (0 ^ sl) * 4);
        f32x4 a1 = *(const f32x4*)(ps + (1 ^ sl) * 4);
        f32x4 a2 = *(const f32x4*)(ps + (2 ^ sl) * 4);
        f32x4 a3 = *(const f32x4*)(ps + (3 ^ sl) * 4);
        float d = ebh;
        d += a0[0]*ewh[0] + a0[1]*ewh[1] + a0[2]*ewh[2] + a0[3]*ewh[3];
        d += a1[0]*ewh[4] + a1[1]*ewh[5] + a1[2]*ewh[6] + a1[3]*ewh[7];
        d += a2[0]*ewh[8] + a2[1]*ewh[9] + a2[2]*ewh[10] + a2[3]*ewh[11];
        d += a3[0]*ewh[12] + a3[1]*ewh[13] + a3[2]*ewh[14] + a3[3]*ewh[15];
        bv[nb][r] = d;
      }
    }

    // ---- QK^T ----
    f32x4 sc[4];
#pragma unroll
    for (int nb = 0; nb < 4; ++nb) {
      const u16* kp = Kb + (size_t)(kt + nb * 16 + c) * 64 + 8 * g;
      bf16x8 b0 = *(const bf16x8*)kp;
      bf16x8 b1 = *(const bf16x8*)(kp + 32);
      f32x4 z = (f32x4){0.f, 0.f, 0.f, 0.f};
      z = __builtin_amdgcn_mfma_f32_16x16x32_bf16(qf0, b0, z, 0, 0, 0);
      z = __builtin_amdgcn_mfma_f32_16x16x32_bf16(qf1, b1, z, 0, 0, 0);
      sc[nb] = z;
    }
#pragma unroll
    for (int nb = 0; nb < 4; ++nb)
#pragma unroll
      for (int r = 0; r < 4; ++r) sc[nb][r] += bv[nb][r];

    // ---- online softmax ----
    float mnew[4], scl[4];
#pragma unroll
    for (int r = 0; r < 4; ++r) {
      float mx = fmaxf(fmaxf(sc[0][r], sc[1][r]), fmaxf(sc[2][r], sc[3][r]));
      mx = redmax16(mx);
      mnew[r] = fmaxf(mrow[r], mx);
      scl[r] = __expf(mrow[r] - mnew[r]);
      mrow[r] = mnew[r];
    }
    float rsum[4] = {0.f, 0.f, 0.f, 0.f};
#pragma unroll
    for (int nb = 0; nb < 4; ++nb)
#pragma unroll
      for (int r = 0; r < 4; ++r) {
        float e = __expf(sc[nb][r] - mnew[r]);
        sc[nb][r] = e;
        rsum[r] += e;
      }
#pragma unroll
    for (int r = 0; r < 4; ++r) {
      float s = redsum16(rsum[r]);
      lrow[r] = lrow[r] * scl[r] + s;
    }
#pragma unroll
    for (int nd = 0; nd < 4; ++nd)
#pragma unroll
      for (int r = 0; r < 4; ++r) o[nd][r] *= scl[r];

    // ---- P -> per-wave LDS (bf16, XOR-swizzled) ----
#pragma unroll
    for (int nb = 0; nb < 4; ++nb)
#pragma unroll
      for (int r = 0; r < 4; ++r) {
        int rr = g * 4 + r, kk = nb * 16 + c;
        Pw[rr * 64 + (kk ^ ((rr & 7) << 3))] = f2bf(sc[nb][r]);
      }
    bf16x8 pa0, pa1;
    {
      int rr = c;
      pa0 = *(const bf16x8*)&Pw[rr * 64 + ((8 * g) ^ ((rr & 7) << 3))];
      pa1 = *(const bf16x8*)&Pw[rr * 64 + ((32 + 8 * g) ^ ((rr & 7) << 3))];
    }
    // ---- PV ----
#pragma unroll
    for (int nd = 0; nd < 4; ++nd) {
      const u16* vp = Vb + (size_t)(nd * 16 + c) * 2048 + kt;
      bf16x8 v0 = *(const bf16x8*)(vp + 8 * g);
      bf16x8 v1 = *(const bf16x8*)(vp + 32 + 8 * g);
      o[nd] = __builtin_amdgcn_mfma_f32_16x16x32_bf16(pa0, v0, o[nd], 0, 0, 0);
      o[nd] = __builtin_amdgcn_mfma_f32_16x16x32_bf16(pa1, v1, o[nd], 0, 0, 0);
    }
  }

  // ---- normalize + write ctx ----
  float inv[4];
#pragma unroll
  for (int r = 0; r < 4; ++r) inv[r] = 1.0f / lrow[r];
#pragma unroll
  for (int nd = 0; nd < 4; ++nd)
#pragma unroll
    for (int r = 0; r < 4; ++r) {
      int s_glob = q0 + g * 4 + r;
      ctx[(size_t)(b * 2048 + s_glob) * 512 + h * 64 + nd * 16 + c] =
          f2bf(o[nd][r] * inv[r]);
    }
}

// ------------------------ K4: output projection -----------------------------
__launch_bounds__(256)
__global__ void k_outproj(const u16* __restrict__ ctx, const u16* __restrict__ wobf,
                          const float* __restrict__ bout, float* __restrict__ out) {
  __shared__ __align__(16) u16 As[4096];
  __shared__ __align__(16) u16 Bs[4096];
  const int tid = threadIdx.x, wave = tid >> 6, lane = tid & 63;
  const int g = lane >> 4, c = lane & 15;
  const int wm = wave >> 1, wn = wave & 1;
  const int mt = blockIdx.x, nt = blockIdx.y;
  const u16* W = wobf + (size_t)(nt * 128) * 512;

  f32x4 acc[4][4];
#pragma unroll
  for (int i = 0; i < 4; ++i)
#pragma unroll
    for (int j = 0; j < 4; ++j) acc[i][j] = (f32x4){0.f, 0.f, 0.f, 0.f};

  gemm128_core(ctx, W, As, Bs, mt, acc);

#pragma unroll
  for (int mb = 0; mb < 4; ++mb)
#pragma unroll
    for (int nb = 0; nb < 4; ++nb) {
      int n = nt * 128 + wn * 64 + nb * 16 + c;
      float bv = bout[n];
      int m0 = mt * 128 + wm * 64 + mb * 16 + g * 4;
#pragma unroll
      for (int r = 0; r < 4; ++r)
        out[(size_t)(m0 + r) * 512 + n] = acc[mb][nb][r] + bv;
    }
}

// ---------------------------------------------------------------------------
extern "C" void kernel_launch(void* const* d_in, const int* in_sizes, int n_in,
                              void* d_out, int out_size, void* d_ws, size_t ws_size,
                              hipStream_t stream) {
  (void)in_sizes; (void)n_in; (void)out_size; (void)ws_size;
  const float* q     = (const float*)d_in[0];
  const float* k     = (const float*)d_in[1];
  const float* v     = (const float*)d_in[2];
  const float* p     = (const float*)d_in[3];
  const float* w_in  = (const float*)d_in[4];
  const float* b_in  = (const float*)d_in[5];
  const float* w_out = (const float*)d_in[6];
  const float* b_out = (const float*)d_in[7];
  const float* ew    = (const float*)d_in[8];
  const float* eb    = (const float*)d_in[9];
  float* out = (float*)d_out;

  char* ws = (char*)d_ws;
  size_t off = 0;
  auto alloc = [&](size_t bytes) {
    void* r = ws + off;
    off += (bytes + 255) & ~(size_t)255;
    return r;
  };
  const size_t NTOK = (size_t)NB * NS;  // 4096
  u16* qbf  = (u16*)alloc(NTOK * NE * 2);
  u16* kbf  = (u16*)alloc(NTOK * NE * 2);
  u16* vbf  = (u16*)alloc(NTOK * NE * 2);
  u16* wbf  = (u16*)alloc((size_t)3 * NE * NE * 2);
  u16* wobf = (u16*)alloc((size_t)NE * NE * 2);
  u16* qhb  = (u16*)alloc(NTOK * NE * 2);
  u16* khb  = (u16*)alloc(NTOK * NE * 2);
  u16* vtb  = (u16*)alloc(NTOK * NE * 2);
  u16* ctxb = (u16*)alloc(NTOK * NE * 2);

  // K1: converts
  int n4;
  n4 = (int)(NTOK * NE / 4);
  k_cvt<<<n4 / 256, 256, 0, stream>>>(q, qbf, n4);
  k_cvt<<<n4 / 256, 256, 0, stream>>>(k, kbf, n4);
  k_cvt<<<n4 / 256, 256, 0, stream>>>(v, vbf, n4);
  n4 = 3 * NE * NE / 4;
  k_cvt<<<n4 / 256, 256, 0, stream>>>(w_in, wbf, n4);
  n4 = NE * NE / 4;
  k_cvt<<<n4 / 256, 256, 0, stream>>>(w_out, wobf, n4);

  // K2: projections
  k_proj<<<dim3(32, 12), 256, 0, stream>>>(qbf, kbf, vbf, wbf, b_in, qhb, khb, vtb);

  // K3: fused bias + attention
  k_fattn<<<256, 512, 0, stream>>>(p, ew, eb, qhb, khb, vtb, ctxb);

  // K4: out projection
  k_outproj<<<dim3(32, 4), 256, 0, stream>>>(ctxb, wobf, b_out, out);
}

// Round 4
// 870.394 us; speedup vs baseline: 1.0392x; 1.0272x over previous
//
#include <hip/hip_runtime.h>

// Problem constants: B=2, S=2048, E=512, H=8, D=64, EDGE=16
#define NB 2
#define NS 2048
#define NE 512
#define NH 8
#define ND 64
#define NEDGE 16

typedef unsigned short u16;
typedef __attribute__((ext_vector_type(4))) float f32x4;
typedef __attribute__((ext_vector_type(8))) short bf16x8;

__device__ __forceinline__ u16 f2bf(float f) {
  unsigned u = __float_as_uint(f);
  u += 0x7FFFu + ((u >> 16) & 1u);
  return (u16)(u >> 16);
}
__device__ __forceinline__ float bf2f(u16 h) {
  return __uint_as_float(((unsigned)h) << 16);
}
__device__ __forceinline__ void gload16(const void* g, void* l) {
  __builtin_amdgcn_global_load_lds(
      (const __attribute__((address_space(1))) unsigned*)g,
      (__attribute__((address_space(3))) unsigned*)l, 16, 0, 0);
}
// non-temporal variant: p is stream-once, keep it out of L2 so K/V stay hot
__device__ __forceinline__ void gload16nt(const void* g, void* l) {
  __builtin_amdgcn_global_load_lds(
      (const __attribute__((address_space(1))) unsigned*)g,
      (__attribute__((address_space(3))) unsigned*)l, 16, 0, 2);
}

// ------------------------- K1: f32 -> bf16 convert -------------------------
__global__ void k_cvt(const float* __restrict__ in, u16* __restrict__ out, int n4) {
  int i = blockIdx.x * 256 + threadIdx.x;
  if (i >= n4) return;
  float4 v = ((const float4*)in)[i];
  ushort4 o;
  o.x = f2bf(v.x); o.y = f2bf(v.y); o.z = f2bf(v.z); o.w = f2bf(v.w);
  ((ushort4*)out)[i] = o;
}

// --------------------- shared 128x128 GEMM core (K=512) ---------------------
__device__ __forceinline__ void gemm128_core(const u16* __restrict__ A,
                                             const u16* __restrict__ W,
                                             u16* As, u16* Bs,
                                             int mt, f32x4 acc[4][4]) {
  const int tid = threadIdx.x, wave = tid >> 6, lane = tid & 63;
  const int g = lane >> 4, c = lane & 15;
  const int wm = wave >> 1, wn = wave & 1;
  for (int kt = 0; kt < 16; ++kt) {
#pragma unroll
    for (int r = 0; r < 2; ++r) {
      int seg = wave + 4 * r;
      int idx = seg * 64 + lane;
      int row = idx >> 2, colB = idx & 3;
      gload16(A + (size_t)(mt * 128 + row) * 512 + kt * 32 + colB * 8,
              (char*)As + seg * 1024);
      gload16(W + (size_t)row * 512 + kt * 32 + colB * 8,
              (char*)Bs + seg * 1024);
    }
    __syncthreads();
    bf16x8 af[4], bw[4];
#pragma unroll
    for (int mb = 0; mb < 4; ++mb)
      af[mb] = *(const bf16x8*)&As[(wm * 64 + mb * 16 + c) * 32 + 8 * g];
#pragma unroll
    for (int nb = 0; nb < 4; ++nb)
      bw[nb] = *(const bf16x8*)&Bs[(wn * 64 + nb * 16 + c) * 32 + 8 * g];
#pragma unroll
    for (int mb = 0; mb < 4; ++mb)
#pragma unroll
      for (int nb = 0; nb < 4; ++nb)
        acc[mb][nb] = __builtin_amdgcn_mfma_f32_16x16x32_bf16(
            af[mb], bw[nb], acc[mb][nb], 0, 0, 0);
    __syncthreads();
  }
}

// ------------------- K2: packed QKV projection (bf16 MFMA) ------------------
__launch_bounds__(256)
__global__ void k_proj(const u16* __restrict__ qbf, const u16* __restrict__ kbf,
                       const u16* __restrict__ vbf, const u16* __restrict__ wbf,
                       const float* __restrict__ bin,
                       u16* __restrict__ qh, u16* __restrict__ kh,
                       u16* __restrict__ vt) {
  __shared__ __align__(16) u16 As[4096];
  __shared__ __align__(16) u16 Bs[4096];
  const int tid = threadIdx.x, wave = tid >> 6, lane = tid & 63;
  const int g = lane >> 4, c = lane & 15;
  const int wm = wave >> 1, wn = wave & 1;
  const int mt = blockIdx.x;
  const int chunk = blockIdx.y >> 2, ntl = blockIdx.y & 3;
  const u16* A = chunk == 0 ? qbf : (chunk == 1 ? kbf : vbf);
  const u16* W = wbf + (size_t)(chunk * 512 + ntl * 128) * 512;

  f32x4 acc[4][4];
#pragma unroll
  for (int i = 0; i < 4; ++i)
#pragma unroll
    for (int j = 0; j < 4; ++j) acc[i][j] = (f32x4){0.f, 0.f, 0.f, 0.f};

  gemm128_core(A, W, As, Bs, mt, acc);

#pragma unroll
  for (int mb = 0; mb < 4; ++mb) {
#pragma unroll
    for (int nb = 0; nb < 4; ++nb) {
      int ncl = ntl * 128 + wn * 64 + nb * 16 + c;
      float bv = bin[chunk * 512 + ncl];
      int h = ncl >> 6, d = ncl & 63;
      int m0 = mt * 128 + wm * 64 + mb * 16 + g * 4;
      int b = m0 >> 11, s0 = m0 & 2047;
      if (chunk == 2) {
        ushort4 o;
        o.x = f2bf(acc[mb][nb][0] + bv);
        o.y = f2bf(acc[mb][nb][1] + bv);
        o.z = f2bf(acc[mb][nb][2] + bv);
        o.w = f2bf(acc[mb][nb][3] + bv);
        *(ushort4*)&vt[((size_t)(b * 8 + h) * 64 + d) * 2048 + s0] = o;
      } else {
        u16* dst = (chunk == 0) ? qh : kh;
        float sc = (chunk == 0) ? 0.125f : 1.0f;
#pragma unroll
        for (int r = 0; r < 4; ++r)
          dst[((size_t)(b * 8 + h) * 2048 + s0 + r) * 64 + d] =
              f2bf((acc[mb][nb][r] + bv) * sc);
      }
    }
  }
}

// ------------- K3: fused edge-bias + flash attention (all heads) ------------
// block = (b, 16 q-rows); 512 threads = 8 waves = 8 heads.
// p tile [16q][64k][16e] f32 double-buffered in LDS (NT loads).
// Bias via MFMA: [1024 pairs x 16e] x [16e x 8h], K zero-padded to 32.
// aux LDS (16KB) is time-shared: bias bf16 [16q][64k][8h]  <->  per-wave P.
__device__ __forceinline__ float redmax16(float x) {
  x = fmaxf(x, __shfl_xor(x, 1));
  x = fmaxf(x, __shfl_xor(x, 2));
  x = fmaxf(x, __shfl_xor(x, 4));
  x = fmaxf(x, __shfl_xor(x, 8));
  return x;
}
__device__ __forceinline__ float redsum16(float x) {
  x += __shfl_xor(x, 1); x += __shfl_xor(x, 2);
  x += __shfl_xor(x, 4); x += __shfl_xor(x, 8);
  return x;
}

__launch_bounds__(512, 2)
__global__ void k_fattn(const float* __restrict__ p,
                        const float* __restrict__ ewg, const float* __restrict__ ebg,
                        const u16* __restrict__ qh, const u16* __restrict__ kh,
                        const u16* __restrict__ vt, u16* __restrict__ ctx) {
  __shared__ __align__(16) float p_s[2][16384];   // 2 x 64 KB
  __shared__ __align__(16) u16 aux[8192];         // 16 KB union (bias | P)
  const int tid = threadIdx.x;
  const int wave = tid >> 6, lane = tid & 63;
  const int g = lane >> 4, c = lane & 15;
  const int h = wave;
  const int bid = blockIdx.x;
  const int xcd = bid & 7, idx = bid >> 3;
  const int b = xcd >> 2;
  const int qt = (xcd & 3) * 32 + idx;   // 0..127
  const int q0 = qt * 16;
  const int bh = b * 8 + h;
  u16* Pw = aux + wave * 1024;

  // B-fragment for bias MFMA: lane (col=c, kgrp=g) holds ew[c][g*8+i]
  // (zero for c>=8 or e>=16 -> K zero-padding)
  bf16x8 ewf;
#pragma unroll
  for (int i = 0; i < 8; ++i) {
    int e = g * 8 + i;
    float val = (c < 8 && e < 16) ? ewg[c * 16 + e] : 0.f;
    ewf[i] = (short)f2bf(val);
  }
  const float ebv = (c < 8) ? ebg[c] : 0.f;

  // Q fragments (16 rows), hoisted
  const u16* Qb = qh + ((size_t)bh * 2048 + q0 + c) * 64;
  bf16x8 qf0 = *(const bf16x8*)(Qb + 8 * g);
  bf16x8 qf1 = *(const bf16x8*)(Qb + 32 + 8 * g);
  const u16* Kb = kh + (size_t)bh * 2048 * 64;
  const u16* Vb = vt + (size_t)bh * 64 * 2048;

  // p staging offsets: LDS slot u = q*256 + k*4 + ecp holds logical chunk
  // ecl = ecp ^ ((k>>1)&3)  (source pre-swizzle; LDS dest linear)
  const float* pb = p + (size_t)(b * 2048 + q0) * 2048 * 16;
  int soff[8], doff[8];
#pragma unroll
  for (int i = 0; i < 8; ++i) {
    int u = i * 512 + tid;
    int ecp = u & 3, kk = (u >> 2) & 63, qq = u >> 8;
    int ecl = ecp ^ ((kk >> 1) & 3);
    soff[i] = (qq * 2048 + kk) * 16 + ecl * 4;
    doff[i] = u * 16;
  }

  f32x4 o[4];
#pragma unroll
  for (int i = 0; i < 4; ++i) o[i] = (f32x4){0.f, 0.f, 0.f, 0.f};
  float mrow[4] = {-1e30f, -1e30f, -1e30f, -1e30f};
  float lrow[4] = {0.f, 0.f, 0.f, 0.f};

  // prologue: stage tile 0 into buffer 0
#pragma unroll
  for (int i = 0; i < 8; ++i)
    gload16nt(pb + soff[i], (char*)p_s + doff[i]);

  for (int t = 0; t < 32; ++t) {
    const int kt = t * 64;
    asm volatile("s_waitcnt vmcnt(0)" ::: "memory");
    __builtin_amdgcn_s_barrier();
    __builtin_amdgcn_sched_barrier(0);
    if (t < 31) {
      const float* src = pb + (size_t)(kt + 64) * 16;
      char* dst = (char*)p_s + ((t + 1) & 1) * 65536;
#pragma unroll
      for (int i = 0; i < 8; ++i)
        gload16nt(src + soff[i], dst + doff[i]);
    }
    __builtin_amdgcn_sched_barrier(0);
    const float* pc = p_s[t & 1];

    // ---- bias phase: 8 MFMAs per wave, pairs [wave*128, wave*128+128) ----
#pragma unroll
    for (int m = 0; m < 8; ++m) {
      bf16x8 af;
      if (g < 2) {
        int pairl = wave * 128 + m * 16 + c;
        int qloc = pairl >> 6;          // 0..15
        int kk = pairl & 63;
        int swz = (kk >> 1) & 3;
        const float* ps = pc + (qloc * 256 + kk * 4) * 4;
        f32x4 a0 = *(const f32x4*)(ps + ((2 * g) ^ swz) * 4);
        f32x4 a1 = *(const f32x4*)(ps + ((2 * g + 1) ^ swz) * 4);
        af[0] = (short)f2bf(a0[0]); af[1] = (short)f2bf(a0[1]);
        af[2] = (short)f2bf(a0[2]); af[3] = (short)f2bf(a0[3]);
        af[4] = (short)f2bf(a1[0]); af[5] = (short)f2bf(a1[1]);
        af[6] = (short)f2bf(a1[2]); af[7] = (short)f2bf(a1[3]);
      } else {
        af = (bf16x8){0, 0, 0, 0, 0, 0, 0, 0};   // K zero-pad (e>=16)
      }
      f32x4 cz = (f32x4){0.f, 0.f, 0.f, 0.f};
      f32x4 bc = __builtin_amdgcn_mfma_f32_16x16x32_bf16(af, ewf, cz, 0, 0, 0);
      if (c < 8) {
#pragma unroll
        for (int i = 0; i < 4; ++i) {
          int pairl = wave * 128 + m * 16 + g * 4 + i;
          int qloc = pairl >> 6, kk = pairl & 63;
          int kp = kk ^ ((qloc >> 2) << 2);      // bank-spread swizzle
          aux[(qloc * 64 + kp) * 8 + c] = f2bf(bc[i] + ebv);
        }
      }
    }
    // barrier2: bias writes visible to all waves (NO vmcnt drain!)
    asm volatile("s_waitcnt lgkmcnt(0)" ::: "memory");
    __builtin_amdgcn_s_barrier();
    __builtin_amdgcn_sched_barrier(0);

    // ---- read own head's bias fragment ----
    float bv[4][4];
#pragma unroll
    for (int nb = 0; nb < 4; ++nb)
#pragma unroll
      for (int r = 0; r < 4; ++r) {
        int qloc = g * 4 + r;
        int kp = (nb * 16 + c) ^ (g << 2);
        bv[nb][r] = bf2f(aux[(qloc * 64 + kp) * 8 + h]);
      }
    // barrier3: bias reads done before any wave's P writes reuse aux
    asm volatile("s_waitcnt lgkmcnt(0)" ::: "memory");
    __builtin_amdgcn_s_barrier();
    __builtin_amdgcn_sched_barrier(0);

    // ---- QK^T ----
    f32x4 sc[4];
#pragma unroll
    for (int nb = 0; nb < 4; ++nb) {
      const u16* kp = Kb + (size_t)(kt + nb * 16 + c) * 64 + 8 * g;
      bf16x8 b0 = *(const bf16x8*)kp;
      bf16x8 b1 = *(const bf16x8*)(kp + 32);
      f32x4 z = (f32x4){0.f, 0.f, 0.f, 0.f};
      z = __builtin_amdgcn_mfma_f32_16x16x32_bf16(qf0, b0, z, 0, 0, 0);
      z = __builtin_amdgcn_mfma_f32_16x16x32_bf16(qf1, b1, z, 0, 0, 0);
      sc[nb] = z;
    }
#pragma unroll
    for (int nb = 0; nb < 4; ++nb)
#pragma unroll
      for (int r = 0; r < 4; ++r) sc[nb][r] += bv[nb][r];

    // ---- online softmax ----
    float mnew[4], scl[4];
#pragma unroll
    for (int r = 0; r < 4; ++r) {
      float mx = fmaxf(fmaxf(sc[0][r], sc[1][r]), fmaxf(sc[2][r], sc[3][r]));
      mx = redmax16(mx);
      mnew[r] = fmaxf(mrow[r], mx);
      scl[r] = __expf(mrow[r] - mnew[r]);
      mrow[r] = mnew[r];
    }
    float rsum[4] = {0.f, 0.f, 0.f, 0.f};
#pragma unroll
    for (int nb = 0; nb < 4; ++nb)
#pragma unroll
      for (int r = 0; r < 4; ++r) {
        float e = __expf(sc[nb][r] - mnew[r]);
        sc[nb][r] = e;
        rsum[r] += e;
      }
#pragma unroll
    for (int r = 0; r < 4; ++r) {
      float s = redsum16(rsum[r]);
      lrow[r] = lrow[r] * scl[r] + s;
    }
#pragma unroll
    for (int nd = 0; nd < 4; ++nd)
#pragma unroll
      for (int r = 0; r < 4; ++r) o[nd][r] *= scl[r];

    // ---- P -> per-wave LDS (bf16, XOR-swizzled) ----
#pragma unroll
    for (int nb = 0; nb < 4; ++nb)
#pragma unroll
      for (int r = 0; r < 4; ++r) {
        int rr = g * 4 + r, kk = nb * 16 + c;
        Pw[rr * 64 + (kk ^ ((rr & 7) << 3))] = f2bf(sc[nb][r]);
      }
    bf16x8 pa0, pa1;
    {
      int rr = c;
      pa0 = *(const bf16x8*)&Pw[rr * 64 + ((8 * g) ^ ((rr & 7) << 3))];
      pa1 = *(const bf16x8*)&Pw[rr * 64 + ((32 + 8 * g) ^ ((rr & 7) << 3))];
    }
    // ---- PV ----
#pragma unroll
    for (int nd = 0; nd < 4; ++nd) {
      const u16* vp = Vb + (size_t)(nd * 16 + c) * 2048 + kt;
      bf16x8 v0 = *(const bf16x8*)(vp + 8 * g);
      bf16x8 v1 = *(const bf16x8*)(vp + 32 + 8 * g);
      o[nd] = __builtin_amdgcn_mfma_f32_16x16x32_bf16(pa0, v0, o[nd], 0, 0, 0);
      o[nd] = __builtin_amdgcn_mfma_f32_16x16x32_bf16(pa1, v1, o[nd], 0, 0, 0);
    }
  }

  // ---- normalize + write ctx ----
  float inv[4];
#pragma unroll
  for (int r = 0; r < 4; ++r) inv[r] = 1.0f / lrow[r];
#pragma unroll
  for (int nd = 0; nd < 4; ++nd)
#pragma unroll
    for (int r = 0; r < 4; ++r) {
      int s_glob = q0 + g * 4 + r;
      ctx[(size_t)(b * 2048 + s_glob) * 512 + h * 64 + nd * 16 + c] =
          f2bf(o[nd][r] * inv[r]);
    }
}

// ------------------------ K4: output projection -----------------------------
__launch_bounds__(256)
__global__ void k_outproj(const u16* __restrict__ ctx, const u16* __restrict__ wobf,
                          const float* __restrict__ bout, float* __restrict__ out) {
  __shared__ __align__(16) u16 As[4096];
  __shared__ __align__(16) u16 Bs[4096];
  const int tid = threadIdx.x, wave = tid >> 6, lane = tid & 63;
  const int g = lane >> 4, c = lane & 15;
  const int wm = wave >> 1, wn = wave & 1;
  const int mt = blockIdx.x, nt = blockIdx.y;
  const u16* W = wobf + (size_t)(nt * 128) * 512;

  f32x4 acc[4][4];
#pragma unroll
  for (int i = 0; i < 4; ++i)
#pragma unroll
    for (int j = 0; j < 4; ++j) acc[i][j] = (f32x4){0.f, 0.f, 0.f, 0.f};

  gemm128_core(ctx, W, As, Bs, mt, acc);

#pragma unroll
  for (int mb = 0; mb < 4; ++mb)
#pragma unroll
    for (int nb = 0; nb < 4; ++nb) {
      int n = nt * 128 + wn * 64 + nb * 16 + c;
      float bv = bout[n];
      int m0 = mt * 128 + wm * 64 + mb * 16 + g * 4;
#pragma unroll
      for (int r = 0; r < 4; ++r)
        out[(size_t)(m0 + r) * 512 + n] = acc[mb][nb][r] + bv;
    }
}

// ---------------------------------------------------------------------------
extern "C" void kernel_launch(void* const* d_in, const int* in_sizes, int n_in,
                              void* d_out, int out_size, void* d_ws, size_t ws_size,
                              hipStream_t stream) {
  (void)in_sizes; (void)n_in; (void)out_size; (void)ws_size;
  const float* q     = (const float*)d_in[0];
  const float* k     = (const float*)d_in[1];
  const float* v     = (const float*)d_in[2];
  const float* p     = (const float*)d_in[3];
  const float* w_in  = (const float*)d_in[4];
  const float* b_in  = (const float*)d_in[5];
  const float* w_out = (const float*)d_in[6];
  const float* b_out = (const float*)d_in[7];
  const float* ew    = (const float*)d_in[8];
  const float* eb    = (const float*)d_in[9];
  float* out = (float*)d_out;

  char* ws = (char*)d_ws;
  size_t off = 0;
  auto alloc = [&](size_t bytes) {
    void* r = ws + off;
    off += (bytes + 255) & ~(size_t)255;
    return r;
  };
  const size_t NTOK = (size_t)NB * NS;  // 4096
  u16* qbf  = (u16*)alloc(NTOK * NE * 2);
  u16* kbf  = (u16*)alloc(NTOK * NE * 2);
  u16* vbf  = (u16*)alloc(NTOK * NE * 2);
  u16* wbf  = (u16*)alloc((size_t)3 * NE * NE * 2);
  u16* wobf = (u16*)alloc((size_t)NE * NE * 2);
  u16* qhb  = (u16*)alloc(NTOK * NE * 2);
  u16* khb  = (u16*)alloc(NTOK * NE * 2);
  u16* vtb  = (u16*)alloc(NTOK * NE * 2);
  u16* ctxb = (u16*)alloc(NTOK * NE * 2);

  // K1: converts
  int n4;
  n4 = (int)(NTOK * NE / 4);
  k_cvt<<<n4 / 256, 256, 0, stream>>>(q, qbf, n4);
  k_cvt<<<n4 / 256, 256, 0, stream>>>(k, kbf, n4);
  k_cvt<<<n4 / 256, 256, 0, stream>>>(v, vbf, n4);
  n4 = 3 * NE * NE / 4;
  k_cvt<<<n4 / 256, 256, 0, stream>>>(w_in, wbf, n4);
  n4 = NE * NE / 4;
  k_cvt<<<n4 / 256, 256, 0, stream>>>(w_out, wobf, n4);

  // K2: projections
  k_proj<<<dim3(32, 12), 256, 0, stream>>>(qbf, kbf, vbf, wbf, b_in, qhb, khb, vtb);

  // K3: fused bias + attention
  k_fattn<<<256, 512, 0, stream>>>(p, ew, eb, qhb, khb, vtb, ctxb);

  // K4: out projection
  k_outproj<<<dim3(32, 4), 256, 0, stream>>>(ctxb, wobf, b_out, out);
}